// Round 5
// baseline (1082.516 us; speedup 1.0000x reference)
//
#include <hip/hip_runtime.h>
#include <hip/hip_cooperative_groups.h>
#include <math.h>

namespace cg = cooperative_groups;

// ---------------------------------------------------------------------------
// RoutingNet round 5: single cooperative mega-kernel, 9 phases, grid.sync()
// between phases. 768 blocks x 256 thr, <=39KB LDS, launch_bounds(256,3)
// => 3 blocks/CU co-resident guaranteed. Fallback: per-phase launches.
// ---------------------------------------------------------------------------

#define BN_SCALE rsqrtf(1.0f + 1e-5f)

struct KParams {
  const float *support, *query;
  const float *w0, *g0, *b0;
  const float *w1, *g1, *b1;
  const float *w2, *g2, *b2;
  const float *w3, *g3, *b3;
  const float *w4, *g4, *b4;
  const float *tw, *tb, *bw, *sw, *sb;
  float *out;
  float *ws;
};

// ws offsets (floats)
#define OFF_A0    0
#define OFF_A1    4096000
#define OFF_A2    4608000
#define OFF_A3    4864000
#define OFF_FEATS 4992000
#define OFF_E     5056000
#define OFF_PROTO 5081600
#define OFF_T1    5084160
#define OFF_W1T   5340160
#define OFF_W2T   5344768
#define OFF_W3T   5363200
#define OFF_W4T   5436928
#define OFF_TWT   5731840

__global__ void __launch_bounds__(256, 3)
k_mega(KParams P, int p_lo, int p_hi, int coop) {
  __shared__ float smem[9792];   // 39168 B, unioned across phases
  cg::grid_group gg = cg::this_grid();
  const int t = threadIdx.x;
  const int bid = blockIdx.x;
  const int grid = gridDim.x;
  const int lane = t & 63, wid = t >> 6;

  float* a0    = P.ws + OFF_A0;
  float* a1    = P.ws + OFF_A1;
  float* a2    = P.ws + OFF_A2;
  float* a3    = P.ws + OFF_A3;
  float* feats = P.ws + OFF_FEATS;
  float* e_buf = P.ws + OFF_E;
  float* proto = P.ws + OFF_PROTO;
  float* t1    = P.ws + OFF_T1;
  float* w1t   = P.ws + OFF_W1T;
  float* w2t   = P.ws + OFF_W2T;
  float* w3t   = P.ws + OFF_W3T;
  float* w4t   = P.ws + OFF_W4T;
  float* twt   = P.ws + OFF_TWT;

  for (int p = p_lo; p <= p_hi; ++p) {
    switch (p) {
      case 0: {
        // ---- block0: 1->16ch, 128x128 -s2-> 64x64 -pool-> 32x32 ----
        for (int task = bid; task < 1000; task += grid) {
          int img = task >> 2, band = task & 3;
          const float* in = (img < 100) ? (P.support + (size_t)img * 16384)
                                        : (P.query + (size_t)(img - 100) * 16384);
          int row0 = band * 32 - 1;
          if (t < 33) smem[t * 132] = 0.f;
          for (int i = t; i < 33 * 128; i += 256) {
            int r = i >> 7, cc = i & 127;
            int ry = row0 + r;
            smem[r * 132 + cc + 1] = (ry >= 0) ? in[ry * 128 + cc] : 0.f;
          }
          __syncthreads();
          int ox = lane & 31, oyh = lane >> 5;
          int oc0 = wid * 4;
          float wv[36], sc[4], bs[4];
#pragma unroll
          for (int j = 0; j < 4; j++) {
#pragma unroll
            for (int k = 0; k < 9; k++) wv[j * 9 + k] = P.w0[(oc0 + j) * 9 + k];
            sc[j] = P.g0[oc0 + j] * BN_SCALE;
            bs[j] = P.b0[oc0 + j];
          }
#pragma unroll
          for (int oyy = 0; oyy < 4; oyy++) {
            int oy = oyy * 2 + oyh;
            float win[25];
#pragma unroll
            for (int d = 0; d < 5; d++) {
              const float* rp = smem + (4 * oy + d) * 132 + 4 * ox;
              float4 r4 = *(const float4*)rp;
              win[d * 5 + 0] = r4.x; win[d * 5 + 1] = r4.y;
              win[d * 5 + 2] = r4.z; win[d * 5 + 3] = r4.w;
              win[d * 5 + 4] = rp[4];
            }
#pragma unroll
            for (int j = 0; j < 4; j++) {
              float m = -1e30f;
#pragma unroll
              for (int py = 0; py < 2; py++)
#pragma unroll
                for (int px = 0; px < 2; px++) {
                  float c = 0.f;
#pragma unroll
                  for (int ky = 0; ky < 3; ky++)
#pragma unroll
                    for (int kx = 0; kx < 3; kx++)
                      c = fmaf(win[(2 * py + ky) * 5 + (2 * px + kx)],
                               wv[j * 9 + ky * 3 + kx], c);
                  m = fmaxf(m, fmaf(c, sc[j], bs[j]));
                }
              int OY = band * 8 + oy;
              a0[(((size_t)img * 16 + oc0 + j) * 32 + OY) * 32 + ox] = fmaxf(m, 0.f);
            }
          }
          __syncthreads();
        }
        // ---- transposes + t1 zero (flat) ----
        for (int i = bid * 256 + t; i < 713216; i += grid * 256) {
          if (i < 4608) {                       // w1t: OC=32, IC=16
            int oc = i & 31; int r = i >> 5; int tap = r % 9; int ic = r / 9;
            w1t[i] = P.w1[(oc * 16 + ic) * 9 + tap];
          } else if (i < 23040) {               // w2t: OC=64, IC=32
            int j = i - 4608;
            int oc = j & 63; int r = j >> 6; int tap = r % 9; int ic = r / 9;
            w2t[j] = P.w2[(oc * 32 + ic) * 9 + tap];
          } else if (i < 96768) {               // w3t: OC=128, IC=64
            int j = i - 23040;
            int oc = j & 127; int r = j >> 7; int tap = r % 9; int ic = r / 9;
            w3t[j] = P.w3[(oc * 64 + ic) * 9 + tap];
          } else if (i < 391680) {              // w4t: OC=256, IC=128
            int j = i - 96768;
            int oc = j & 255; int r = j >> 8; int tap = r % 9; int ic = r / 9;
            w4t[j] = P.w4[(oc * 128 + ic) * 9 + tap];
          } else if (i < 457216) {              // twt[d][c] = tw[c][d]
            int j = i - 391680;
            int d = j >> 8, c = j & 255;
            twt[j] = P.tw[c * 256 + d];
          } else {
            t1[i - 457216] = 0.f;
          }
        }
        break;
      }
      case 1: {
        // ---- block1: 16->32ch, 32x32 -s2-> 16x16 -pool-> 8x8. 500 tasks ----
        for (int task = bid; task < 500; task += grid) {
          int img = task >> 1, OY0 = (task & 1) * 4;
          int R0 = OY0 * 4 - 1;
          const float* in = a0 + (size_t)img * 16384;
          for (int i = t; i < 9792; i += 256) {
            int c = i % 36; int rr = (i / 36) % 17; int ic = i / 612;
            int gr = R0 + rr, gc = c - 1;
            smem[i] = (c >= 1 && c <= 32 && gr >= 0) ? in[ic * 1024 + gr * 32 + gc] : 0.f;
          }
          __syncthreads();
          int pos = t & 31, og = t >> 5;
          int oxl = pos & 7, oyl = pos >> 3;
          float acc[4][4];
#pragma unroll
          for (int j = 0; j < 4; j++)
#pragma unroll
            for (int q = 0; q < 4; q++) acc[j][q] = 0.f;
          for (int ic = 0; ic < 16; ic++) {
            float win[25];
#pragma unroll
            for (int d = 0; d < 5; d++) {
              const float* rp = smem + ic * 612 + (4 * oyl + d) * 36 + 4 * oxl;
              float4 r4 = *(const float4*)rp;
              win[d * 5 + 0] = r4.x; win[d * 5 + 1] = r4.y;
              win[d * 5 + 2] = r4.z; win[d * 5 + 3] = r4.w;
              win[d * 5 + 4] = rp[4];
            }
#pragma unroll
            for (int j = 0; j < 4; j++) {
              int oc = og * 4 + j;
              const float* wp = w1t + ic * 288 + oc;   // [(ic*9+tap)*32+oc]
              float wr[9];
#pragma unroll
              for (int k = 0; k < 9; k++) wr[k] = wp[k * 32];
#pragma unroll
              for (int py = 0; py < 2; py++)
#pragma unroll
                for (int px = 0; px < 2; px++) {
                  float c = acc[j][py * 2 + px];
#pragma unroll
                  for (int ky = 0; ky < 3; ky++)
#pragma unroll
                    for (int kx = 0; kx < 3; kx++)
                      c = fmaf(win[(2 * py + ky) * 5 + (2 * px + kx)], wr[ky * 3 + kx], c);
                  acc[j][py * 2 + px] = c;
                }
            }
          }
#pragma unroll
          for (int j = 0; j < 4; j++) {
            int oc = og * 4 + j;
            float sc = P.g1[oc] * BN_SCALE, bsj = P.b1[oc];
            float m = -1e30f;
#pragma unroll
            for (int q = 0; q < 4; q++) m = fmaxf(m, fmaf(acc[j][q], sc, bsj));
            a1[(size_t)img * 2048 + oc * 64 + (OY0 + oyl) * 8 + oxl] = fmaxf(m, 0.f);
          }
          __syncthreads();
        }
        break;
      }
      case 2: {
        // ---- conv2: 32->64ch, 8x8 -> pool 4x4. 1000 tasks (img x prow) ----
        for (int task = bid; task < 1000; task += grid) {
          int img = task >> 2, prow = task & 3;
          int R0 = 2 * prow - 1;
          const float* ap = a1 + (size_t)img * 2048;
          for (int i = t; i < 1536; i += 256) {
            int c = i % 12; int r = (i / 12) & 3; int ic = i / 48;
            int gr = R0 + r, gc = c - 1;
            smem[i] = (c >= 1 && c <= 8 && gr >= 0 && gr < 8) ? ap[ic * 64 + gr * 8 + gc] : 0.f;
          }
          __syncthreads();
          int oc = t & 63, pc = t >> 6;    // 64 oc x 4 pooled cols
          float acc[4] = {0.f, 0.f, 0.f, 0.f};
          for (int ic = 0; ic < 32; ic++) {
            float win[4][4];
#pragma unroll
            for (int r = 0; r < 4; r++) {
              const float2* rp = (const float2*)(smem + ic * 48 + r * 12 + 2 * pc);
              float2 u = rp[0], v = rp[1];
              win[r][0] = u.x; win[r][1] = u.y; win[r][2] = v.x; win[r][3] = v.y;
            }
            const float* wp = w2t + ic * 576 + oc;
            float wr[9];
#pragma unroll
            for (int k = 0; k < 9; k++) wr[k] = wp[k * 64];
#pragma unroll
            for (int py = 0; py < 2; py++)
#pragma unroll
              for (int px = 0; px < 2; px++) {
                float c = acc[py * 2 + px];
#pragma unroll
                for (int ky = 0; ky < 3; ky++)
#pragma unroll
                  for (int kx = 0; kx < 3; kx++)
                    c = fmaf(win[py + ky][px + kx], wr[ky * 3 + kx], c);
                acc[py * 2 + px] = c;
              }
          }
          float sc = P.g2[oc] * BN_SCALE, bsj = P.b2[oc];
          float m = -1e30f;
#pragma unroll
          for (int q = 0; q < 4; q++) m = fmaxf(m, fmaf(acc[q], sc, bsj));
          a2[(size_t)img * 1024 + oc * 16 + prow * 4 + pc] = fmaxf(m, 0.f);
          __syncthreads();
        }
        break;
      }
      case 3: {
        // ---- conv3: 64->128ch, 4x4 -> pool 2x2. 500 tasks (img x och) ----
        for (int task = bid; task < 500; task += grid) {
          int img = task >> 1, och = task & 1;
          const float* ap = a2 + (size_t)img * 1024;
          for (int i = t; i < 3072; i += 256) {
            int c = i & 7; int r = (i >> 3) % 6; int ic = i / 48;
            int gr = r - 1, gc = c - 1;
            smem[i] = (c >= 1 && c <= 4 && r >= 1 && r <= 4) ? ap[ic * 16 + gr * 4 + gc] : 0.f;
          }
          __syncthreads();
          int oc = och * 64 + (t & 63), pg = t >> 6;
          int py = pg >> 1, px = pg & 1;
          float acc[4] = {0.f, 0.f, 0.f, 0.f};
          for (int ic = 0; ic < 64; ic++) {
            float win[4][4];
#pragma unroll
            for (int r = 0; r < 4; r++) {
              const float2* rp = (const float2*)(smem + ic * 48 + (2 * py + r) * 8 + 2 * px);
              float2 u = rp[0], v = rp[1];
              win[r][0] = u.x; win[r][1] = u.y; win[r][2] = v.x; win[r][3] = v.y;
            }
            const float* wp = w3t + ic * 1152 + oc;
            float wr[9];
#pragma unroll
            for (int k = 0; k < 9; k++) wr[k] = wp[k * 128];
#pragma unroll
            for (int pyy = 0; pyy < 2; pyy++)
#pragma unroll
              for (int pxx = 0; pxx < 2; pxx++) {
                float c = acc[pyy * 2 + pxx];
#pragma unroll
                for (int ky = 0; ky < 3; ky++)
#pragma unroll
                  for (int kx = 0; kx < 3; kx++)
                    c = fmaf(win[pyy + ky][pxx + kx], wr[ky * 3 + kx], c);
                acc[pyy * 2 + pxx] = c;
              }
          }
          float sc = P.g3[oc] * BN_SCALE, bsj = P.b3[oc];
          float m = -1e30f;
#pragma unroll
          for (int q = 0; q < 4; q++) m = fmaxf(m, fmaf(acc[q], sc, bsj));
          a3[(size_t)img * 512 + oc * 4 + pg] = fmaxf(m, 0.f);
          __syncthreads();
        }
        break;
      }
      case 4: {
        // ---- conv4: 128->256ch, 2x2 -> pool 1 -> feats. 500 tasks ----
        for (int task = bid; task < 500; task += grid) {
          int img = task >> 1, och = task & 1;
          float* sIn = smem;          // 512
          float* sP  = smem + 512;    // 1024
          for (int i = t; i < 512; i += 256) sIn[i] = a3[(size_t)img * 512 + i];
          __syncthreads();
          int oc = och * 128 + (t & 127), ich = t >> 7;
          float acc[4] = {0.f, 0.f, 0.f, 0.f};
          for (int ii = 0; ii < 64; ii++) {
            int ic = ich * 64 + ii;
            float4 iv = *(const float4*)(sIn + ic * 4);
            const float* wp = w4t + ic * 2304 + oc;
            float wr[9];
#pragma unroll
            for (int k = 0; k < 9; k++) wr[k] = wp[k * 256];
#pragma unroll
            for (int py = 0; py < 2; py++)
#pragma unroll
              for (int px = 0; px < 2; px++) {
                float c = acc[py * 2 + px];
                c = fmaf(iv.x, wr[(1 - py) * 3 + (1 - px)], c);
                c = fmaf(iv.y, wr[(1 - py) * 3 + (2 - px)], c);
                c = fmaf(iv.z, wr[(2 - py) * 3 + (1 - px)], c);
                c = fmaf(iv.w, wr[(2 - py) * 3 + (2 - px)], c);
                acc[py * 2 + px] = c;
              }
          }
#pragma unroll
          for (int q = 0; q < 4; q++) sP[t * 4 + q] = acc[q];
          __syncthreads();
          if (t < 128) {
            int o = och * 128 + t;
            float sc = P.g4[o] * BN_SCALE, bsj = P.b4[o];
            float m = -1e30f;
#pragma unroll
            for (int q = 0; q < 4; q++)
              m = fmaxf(m, fmaf(sP[t * 4 + q] + sP[(t + 128) * 4 + q], sc, bsj));
            feats[(size_t)img * 256 + o] = fmaxf(m, 0.f);
          }
          __syncthreads();
        }
        break;
      }
      case 5: {
        // ---- e[nk,c] = feats[nk,:] . tw[c,:] + tb[c]  (via twt) ----
        for (int task = bid; task < 100; task += grid) {
          smem[t] = feats[task * 256 + t];
          __syncthreads();
          float acc = P.tb[t];
          const float* wp = twt + t;
#pragma unroll 4
          for (int d = 0; d < 256; d++)
            acc = fmaf(wp[d * 256], smem[d], acc);
          e_buf[task * 256 + t] = acc;
          __syncthreads();
        }
        break;
      }
      case 6: {
        // ---- routing: 10 tasks ----
        float* sb  = smem;        // 10
        float* sdc = smem + 16;   // 10
        float* red = smem + 32;   // 4
        float* red2= smem + 40;   // 40
        float* sfc = smem + 80;   // 1
        for (int n = bid; n < 10; n += grid) {
          float ek[10];
#pragma unroll
          for (int k = 0; k < 10; k++) ek[k] = e_buf[n * 2560 + k * 256 + t];
          if (t < 10) sb[t] = 0.f;
          __syncthreads();
          float cd = 0.f;
          for (int iter = 0; iter < 3; iter++) {
            if (t == 0) {
              float mx = sb[0];
              for (int k = 1; k < 10; k++) mx = fmaxf(mx, sb[k]);
              float sum = 0.f;
              for (int k = 0; k < 10; k++) { float ex = expf(sb[k] - mx); sdc[k] = ex; sum += ex; }
              float inv = 1.f / sum;
              for (int k = 0; k < 10; k++) sdc[k] *= inv;
            }
            __syncthreads();
            cd = 0.f;
#pragma unroll
            for (int k = 0; k < 10; k++) cd = fmaf(sdc[k], ek[k], cd);
            float ss = cd * cd;
#pragma unroll
            for (int off = 32; off > 0; off >>= 1) ss += __shfl_down(ss, off, 64);
            if (lane == 0) red[wid] = ss;
            __syncthreads();
            if (t == 0) {
              float tot = red[0] + red[1] + red[2] + red[3];
              sfc[0] = sqrtf(tot) / (tot + 1.f);
            }
            __syncthreads();
            cd *= sfc[0];
            float pr[10];
#pragma unroll
            for (int k = 0; k < 10; k++) pr[k] = cd * ek[k];
#pragma unroll
            for (int off = 32; off > 0; off >>= 1)
#pragma unroll
              for (int k = 0; k < 10; k++) pr[k] += __shfl_down(pr[k], off, 64);
            if (lane == 0)
#pragma unroll
              for (int k = 0; k < 10; k++) red2[k * 4 + wid] = pr[k];
            __syncthreads();
            if (t < 10) sb[t] += red2[t * 4] + red2[t * 4 + 1] + red2[t * 4 + 2] + red2[t * 4 + 3];
            __syncthreads();
          }
          proto[n * 256 + t] = cd;
          __syncthreads();
        }
        break;
      }
      case 7: {
        // ---- t1 accumulation: 800 tasks (h x 8 c-chunks), atomics ----
        for (int task = bid; task < 800; task += grid) {
          int h = task >> 3, c0 = (task & 7) * 32;
          for (int i = t; i < 320; i += 256) {
            int n = i >> 5, cl = i & 31;
            smem[i] = proto[n * 256 + c0 + cl];
          }
          __syncthreads();
          float acc[10];
#pragma unroll
          for (int n = 0; n < 10; n++) acc[n] = 0.f;
          const float* wp = P.bw + ((size_t)h * 256 + c0) * 256 + t;
#pragma unroll 4
          for (int cl = 0; cl < 32; cl++) {
            float wv = wp[(size_t)cl * 256];
#pragma unroll
            for (int n = 0; n < 10; n++) acc[n] = fmaf(smem[n * 32 + cl], wv, acc[n]);
          }
#pragma unroll
          for (int n = 0; n < 10; n++)
            atomicAdd(&t1[((size_t)n * 100 + h) * 256 + t], acc[n]);
          __syncthreads();
        }
        break;
      }
      case 8: {
        // ---- score + log_softmax: 150 tasks (q) ----
        for (int q = bid; q < 150; q += grid) {
          const float* qf = feats + 100 * 256;
          float4 qv = *(const float4*)(qf + q * 256 + lane * 4);
          float accn[10];
#pragma unroll
          for (int n = 0; n < 10; n++) accn[n] = 0.f;
          for (int h = wid * 25; h < wid * 25 + 25; h++) {
            float swh = P.sw[h];
#pragma unroll
            for (int n = 0; n < 10; n++) {
              float4 tv = *(const float4*)(t1 + ((size_t)n * 100 + h) * 256 + lane * 4);
              float pr = tv.x * qv.x + tv.y * qv.y + tv.z * qv.z + tv.w * qv.w;
#pragma unroll
              for (int off = 32; off > 0; off >>= 1) pr += __shfl_down(pr, off, 64);
              if (lane == 0) accn[n] = fmaf(fmaxf(pr, 0.f), swh, accn[n]);
            }
          }
          if (lane == 0)
#pragma unroll
            for (int n = 0; n < 10; n++) smem[wid * 10 + n] = accn[n];
          __syncthreads();
          if (t == 0) {
            float s[10];
            float mx = -1e30f;
            for (int n = 0; n < 10; n++) {
              s[n] = smem[n] + smem[10 + n] + smem[20 + n] + smem[30 + n] + P.sb[0];
              mx = fmaxf(mx, s[n]);
            }
            float sum = 0.f;
            for (int n = 0; n < 10; n++) sum += expf(s[n] - mx);
            float lse = mx + logf(sum);
            for (int n = 0; n < 10; n++) P.out[q * 10 + n] = s[n] - lse;
          }
          __syncthreads();
        }
        break;
      }
    }
    if (p < p_hi && coop) gg.sync();
  }
}

extern "C" void kernel_launch(void* const* d_in, const int* in_sizes, int n_in,
                              void* d_out, int out_size, void* d_ws, size_t ws_size,
                              hipStream_t stream) {
  KParams kp;
  kp.support = (const float*)d_in[0];
  kp.query   = (const float*)d_in[1];
  kp.w0 = (const float*)d_in[2];  kp.g0 = (const float*)d_in[3];  kp.b0 = (const float*)d_in[4];
  kp.w1 = (const float*)d_in[5];  kp.g1 = (const float*)d_in[6];  kp.b1 = (const float*)d_in[7];
  kp.w2 = (const float*)d_in[8];  kp.g2 = (const float*)d_in[9];  kp.b2 = (const float*)d_in[10];
  kp.w3 = (const float*)d_in[11]; kp.g3 = (const float*)d_in[12]; kp.b3 = (const float*)d_in[13];
  kp.w4 = (const float*)d_in[14]; kp.g4 = (const float*)d_in[15]; kp.b4 = (const float*)d_in[16];
  kp.tw = (const float*)d_in[17]; kp.tb = (const float*)d_in[18];
  kp.bw = (const float*)d_in[19];
  kp.sw = (const float*)d_in[20]; kp.sb = (const float*)d_in[21];
  kp.out = (float*)d_out;
  kp.ws  = (float*)d_ws;

  int p_lo = 0, p_hi = 8, coop = 1;
  void* kargs[] = {&kp, &p_lo, &p_hi, &coop};
  hipError_t err = hipLaunchCooperativeKernel((void*)k_mega, dim3(768), dim3(256),
                                              kargs, 0, stream);
  if (err != hipSuccess) {
    // fallback: per-phase sequential launches (no grid.sync needed)
    for (int p = 0; p <= 8; ++p)
      k_mega<<<1024, 256, 0, stream>>>(kp, p, p, 0);
  }
}

// Round 6
// 237.179 us; speedup vs baseline: 4.5641x; 4.5641x over previous
//
#include <hip/hip_runtime.h>
#include <math.h>

// ---------------------------------------------------------------------------
// RoutingNet round 6: 5 kernels (launch overhead ~10us/kernel; grid.sync is
// ~100us/sync on 8 XCDs -- measured R5 -- so NO cooperative launch).
// k_mid fuses block1..conv4+e per-image at 1024 thr/block (16 waves/CU).
// ---------------------------------------------------------------------------

#define BN_SCALE rsqrtf(1.0f + 1e-5f)

// ws offsets (floats)
#define OFF_A0    0
#define OFF_FEATS 4096000
#define OFF_E     4160000
#define OFF_PROTO 4185600
#define OFF_T1    4188160
#define OFF_W1T   4444160
#define OFF_W2T   4448768
#define OFF_W3T   4467200
#define OFF_W4T   4540928
#define OFF_TWT   4835840

// ---- Kernel 1: block0 conv (1000 tasks) + weight transposes + t1 zero ----
__global__ void k_block0(const float* __restrict__ sup, const float* __restrict__ qry,
                         const float* __restrict__ w0, const float* __restrict__ g0,
                         const float* __restrict__ b0,
                         const float* __restrict__ w1, const float* __restrict__ w2,
                         const float* __restrict__ w3, const float* __restrict__ w4,
                         const float* __restrict__ tw, float* __restrict__ ws) {
  __shared__ float simg[33 * 132];
  float* a0  = ws + OFF_A0;
  float* w1t = ws + OFF_W1T;
  float* w2t = ws + OFF_W2T;
  float* w3t = ws + OFF_W3T;
  float* w4t = ws + OFF_W4T;
  float* twt = ws + OFF_TWT;
  float* t1  = ws + OFF_T1;
  int t = threadIdx.x;
  int task = blockIdx.x;
  int img = task >> 2, band = task & 3;
  const float* in = (img < 100) ? (sup + (size_t)img * 16384)
                                : (qry + (size_t)(img - 100) * 16384);
  int row0 = band * 32 - 1;
  if (t < 33) simg[t * 132] = 0.f;
  for (int i = t; i < 33 * 128; i += 256) {
    int r = i >> 7, cc = i & 127;
    int ry = row0 + r;
    simg[r * 132 + cc + 1] = (ry >= 0) ? in[ry * 128 + cc] : 0.f;
  }
  __syncthreads();
  int lane = t & 63, wid = t >> 6;
  int ox = lane & 31, oyh = lane >> 5;
  int oc0 = wid * 4;
  float wv[36], sc[4], bs[4];
#pragma unroll
  for (int j = 0; j < 4; j++) {
#pragma unroll
    for (int k = 0; k < 9; k++) wv[j * 9 + k] = w0[(oc0 + j) * 9 + k];
    sc[j] = g0[oc0 + j] * BN_SCALE;
    bs[j] = b0[oc0 + j];
  }
#pragma unroll
  for (int oyy = 0; oyy < 4; oyy++) {
    int oy = oyy * 2 + oyh;
    float win[25];
#pragma unroll
    for (int d = 0; d < 5; d++) {
      const float* rp = simg + (4 * oy + d) * 132 + 4 * ox;
      float4 r4 = *(const float4*)rp;
      win[d * 5 + 0] = r4.x; win[d * 5 + 1] = r4.y;
      win[d * 5 + 2] = r4.z; win[d * 5 + 3] = r4.w;
      win[d * 5 + 4] = rp[4];
    }
#pragma unroll
    for (int j = 0; j < 4; j++) {
      float m = -1e30f;
#pragma unroll
      for (int py = 0; py < 2; py++)
#pragma unroll
        for (int px = 0; px < 2; px++) {
          float c = 0.f;
#pragma unroll
          for (int ky = 0; ky < 3; ky++)
#pragma unroll
            for (int kx = 0; kx < 3; kx++)
              c = fmaf(win[(2 * py + ky) * 5 + (2 * px + kx)], wv[j * 9 + ky * 3 + kx], c);
          m = fmaxf(m, fmaf(c, sc[j], bs[j]));
        }
      int OY = band * 8 + oy;
      a0[(((size_t)img * 16 + oc0 + j) * 32 + OY) * 32 + ox] = fmaxf(m, 0.f);
    }
  }
  // tail: weight transposes OIHW->[ic][tap][oc], trans_w transpose, t1 zero
  for (int i = blockIdx.x * 256 + t; i < 713216; i += 256000) {
    if (i < 4608) {
      int oc = i & 31; int r = i >> 5; int tap = r % 9; int ic = r / 9;
      w1t[i] = w1[(oc * 16 + ic) * 9 + tap];
    } else if (i < 23040) {
      int j = i - 4608;
      int oc = j & 63; int r = j >> 6; int tap = r % 9; int ic = r / 9;
      w2t[j] = w2[(oc * 32 + ic) * 9 + tap];
    } else if (i < 96768) {
      int j = i - 23040;
      int oc = j & 127; int r = j >> 7; int tap = r % 9; int ic = r / 9;
      w3t[j] = w3[(oc * 64 + ic) * 9 + tap];
    } else if (i < 391680) {
      int j = i - 96768;
      int oc = j & 255; int r = j >> 8; int tap = r % 9; int ic = r / 9;
      w4t[j] = w4[(oc * 128 + ic) * 9 + tap];
    } else if (i < 457216) {
      int j = i - 391680;
      int d = j >> 8, c = j & 255;
      twt[j] = tw[c * 256 + d];
    } else {
      t1[i - 457216] = 0.f;
    }
  }
}

// ---- Kernel 2: per-image fused block1->conv2->conv3->conv4->e ----
// 250 blocks x 1024 threads (16 waves/CU). All intermediates in LDS.
// LDS layout (floats): [0,19584) L1 input stage (dead after L1; reused:
//   sa2 [0,3072), sa3 [4096,4608), sfeat [4608,4864), RED [8192,~12288))
//   sa1 [19584,23424)
__global__ void __launch_bounds__(1024, 4)
k_mid(const float* __restrict__ g1, const float* __restrict__ b1,
      const float* __restrict__ g2, const float* __restrict__ b2,
      const float* __restrict__ g3, const float* __restrict__ b3,
      const float* __restrict__ g4, const float* __restrict__ b4,
      const float* __restrict__ tb, float* __restrict__ ws,
      float* __restrict__ feats_g, float* __restrict__ e_buf) {
  __shared__ float S[23424];   // 93.7 KB
  const float* a0  = ws + OFF_A0;
  const float* w1t = ws + OFF_W1T;
  const float* w2t = ws + OFF_W2T;
  const float* w3t = ws + OFF_W3T;
  const float* w4t = ws + OFF_W4T;
  const float* twt = ws + OFF_TWT;
  const int img = blockIdx.x;
  const int t = threadIdx.x;
  float* sa1 = S + 19584;   // 32ch x 10 x 12
  float* sa2 = S;           // 64ch x 6 x 8
  float* sa3 = S + 4096;    // 128ch x 4
  float* sft = S + 4608;    // 256
  float* RED = S + 8192;

  // ---- stage a0 image padded (16ch x 34 x 36) + zero sa1 pads ----
  const float* in = a0 + (size_t)img * 16384;
  for (int i = t; i < 19584; i += 1024) {
    int c = i % 36; int r = (i / 36) % 34; int ic = i / 1224;
    int gr = r - 1, gc = c - 1;
    S[i] = (gr >= 0 && gr < 32 && gc >= 0 && gc < 32) ? in[ic * 1024 + gr * 32 + gc] : 0.f;
  }
  for (int i = t; i < 3840; i += 1024) sa1[i] = 0.f;
  __syncthreads();

  // ---- L1: 16->32ch, 32x32 -s2-> 16x16 -pool-> 8x8 ----
  {
    int ocp = t & 15;          // oc pair: 2*ocp, 2*ocp+1
    int pos = t >> 4;          // 64 pooled positions
    int py = pos >> 3, px = pos & 7;
    float acc0[4] = {0.f, 0.f, 0.f, 0.f}, acc1[4] = {0.f, 0.f, 0.f, 0.f};
    for (int ic = 0; ic < 16; ic++) {
      float win[25];
      const float* bp = S + ic * 1224 + 4 * py * 36 + 4 * px;
#pragma unroll
      for (int d = 0; d < 5; d++) {
        float4 r4 = *(const float4*)(bp + d * 36);
        win[d * 5 + 0] = r4.x; win[d * 5 + 1] = r4.y;
        win[d * 5 + 2] = r4.z; win[d * 5 + 3] = r4.w;
        win[d * 5 + 4] = bp[d * 36 + 4];
      }
      float wA[9], wB[9];
#pragma unroll
      for (int k = 0; k < 9; k++) {
        float2 wv = *(const float2*)(w1t + (ic * 9 + k) * 32 + 2 * ocp);
        wA[k] = wv.x; wB[k] = wv.y;
      }
#pragma unroll
      for (int cy = 0; cy < 2; cy++)
#pragma unroll
        for (int cx = 0; cx < 2; cx++) {
          float c0 = acc0[cy * 2 + cx], c1 = acc1[cy * 2 + cx];
#pragma unroll
          for (int ky = 0; ky < 3; ky++)
#pragma unroll
            for (int kx = 0; kx < 3; kx++) {
              float iv = win[(2 * cy + ky) * 5 + (2 * cx + kx)];
              c0 = fmaf(iv, wA[ky * 3 + kx], c0);
              c1 = fmaf(iv, wB[ky * 3 + kx], c1);
            }
          acc0[cy * 2 + cx] = c0; acc1[cy * 2 + cx] = c1;
        }
    }
#pragma unroll
    for (int j = 0; j < 2; j++) {
      int oc = 2 * ocp + j;
      const float* ac = j ? acc1 : acc0;
      float sc = g1[oc] * BN_SCALE, bsj = b1[oc];
      float m = -1e30f;
#pragma unroll
      for (int p = 0; p < 4; p++) m = fmaxf(m, fmaf(ac[p], sc, bsj));
      sa1[oc * 120 + (py + 1) * 12 + (px + 1)] = fmaxf(m, 0.f);
    }
  }
  __syncthreads();
  // zero sa2 pads (region overlapped the now-dead L1 stage)
  for (int i = t; i < 3072; i += 1024) sa2[i] = 0.f;
  __syncthreads();

  // ---- L2: 32->64ch, 8x8 -s1-> 8x8 -pool-> 4x4 ----
  {
    int oc = t & 63, pos = t >> 6;   // 16 pooled positions
    int py = pos >> 2, px = pos & 3;
    float acc[4] = {0.f, 0.f, 0.f, 0.f};
    for (int ic = 0; ic < 32; ic++) {
      float win[16];
      const float* bp = sa1 + ic * 120 + 2 * py * 12 + 2 * px;
#pragma unroll
      for (int r = 0; r < 4; r++) {
        float2 u = *(const float2*)(bp + r * 12);
        float2 v = *(const float2*)(bp + r * 12 + 2);
        win[r * 4 + 0] = u.x; win[r * 4 + 1] = u.y;
        win[r * 4 + 2] = v.x; win[r * 4 + 3] = v.y;
      }
      const float* wp = w2t + ic * 576 + oc;
      float wr[9];
#pragma unroll
      for (int k = 0; k < 9; k++) wr[k] = wp[k * 64];
#pragma unroll
      for (int cy = 0; cy < 2; cy++)
#pragma unroll
        for (int cx = 0; cx < 2; cx++) {
          float c = acc[cy * 2 + cx];
#pragma unroll
          for (int ky = 0; ky < 3; ky++)
#pragma unroll
            for (int kx = 0; kx < 3; kx++)
              c = fmaf(win[(cy + ky) * 4 + (cx + kx)], wr[ky * 3 + kx], c);
          acc[cy * 2 + cx] = c;
        }
    }
    float sc = g2[oc] * BN_SCALE, bsj = b2[oc];
    float m = -1e30f;
#pragma unroll
    for (int p = 0; p < 4; p++) m = fmaxf(m, fmaf(acc[p], sc, bsj));
    sa2[oc * 48 + (py + 1) * 8 + (px + 1)] = fmaxf(m, 0.f);
  }
  __syncthreads();

  // ---- L3: 64->128ch, 4x4 -s1-> 4x4 -pool-> 2x2 (2-way ic split) ----
  {
    int oc = t & 127, pp = (t >> 7) & 3, ich = t >> 9;
    int py = pp >> 1, px = pp & 1;
    float acc[4] = {0.f, 0.f, 0.f, 0.f};
    for (int ii = 0; ii < 32; ii++) {
      int ic = ich * 32 + ii;
      float win[16];
      const float* bp = sa2 + ic * 48 + 2 * py * 8 + 2 * px;
#pragma unroll
      for (int r = 0; r < 4; r++) {
        float2 u = *(const float2*)(bp + r * 8);
        float2 v = *(const float2*)(bp + r * 8 + 2);
        win[r * 4 + 0] = u.x; win[r * 4 + 1] = u.y;
        win[r * 4 + 2] = v.x; win[r * 4 + 3] = v.y;
      }
      const float* wp = w3t + ic * 1152 + oc;
      float wr[9];
#pragma unroll
      for (int k = 0; k < 9; k++) wr[k] = wp[k * 128];
#pragma unroll
      for (int cy = 0; cy < 2; cy++)
#pragma unroll
        for (int cx = 0; cx < 2; cx++) {
          float c = acc[cy * 2 + cx];
#pragma unroll
          for (int ky = 0; ky < 3; ky++)
#pragma unroll
            for (int kx = 0; kx < 3; kx++)
              c = fmaf(win[(cy + ky) * 4 + (cx + kx)], wr[ky * 3 + kx], c);
          acc[cy * 2 + cx] = c;
        }
    }
    if (ich) {
#pragma unroll
      for (int p = 0; p < 4; p++) RED[(t - 512) * 4 + p] = acc[p];
    }
    __syncthreads();
    if (!ich) {
      float sc = g3[oc] * BN_SCALE, bsj = b3[oc];
      float m = -1e30f;
#pragma unroll
      for (int p = 0; p < 4; p++) m = fmaxf(m, fmaf(acc[p] + RED[t * 4 + p], sc, bsj));
      sa3[oc * 4 + pp] = fmaxf(m, 0.f);
    }
  }
  __syncthreads();

  // ---- L4: 128->256ch, 2x2 conv pad1 -> 2x2 -pool-> 1 (4-way ic split) ----
  {
    int oc = t & 255, icq = t >> 8;
    float acc[4] = {0.f, 0.f, 0.f, 0.f};
    for (int ii = 0; ii < 32; ii++) {
      int ic = icq * 32 + ii;
      float4 iv = *(const float4*)(sa3 + ic * 4);
      const float* wp = w4t + ic * 2304 + oc;
      float wr[9];
#pragma unroll
      for (int k = 0; k < 9; k++) wr[k] = wp[k * 256];
#pragma unroll
      for (int py = 0; py < 2; py++)
#pragma unroll
        for (int px = 0; px < 2; px++) {
          float c = acc[py * 2 + px];
          c = fmaf(iv.x, wr[(1 - py) * 3 + (1 - px)], c);
          c = fmaf(iv.y, wr[(1 - py) * 3 + (2 - px)], c);
          c = fmaf(iv.z, wr[(2 - py) * 3 + (1 - px)], c);
          c = fmaf(iv.w, wr[(2 - py) * 3 + (2 - px)], c);
          acc[py * 2 + px] = c;
        }
    }
    if (icq) {
#pragma unroll
      for (int p = 0; p < 4; p++) RED[((icq - 1) * 256 + oc) * 4 + p] = acc[p];
    }
    __syncthreads();
    if (icq == 0) {
      float sc = g4[oc] * BN_SCALE, bsj = b4[oc];
      float m = -1e30f;
#pragma unroll
      for (int p = 0; p < 4; p++) {
        float v = acc[p] + RED[oc * 4 + p] + RED[(256 + oc) * 4 + p] + RED[(512 + oc) * 4 + p];
        m = fmaxf(m, fmaf(v, sc, bsj));
      }
      float r = fmaxf(m, 0.f);
      sft[oc] = r;
      feats_g[(size_t)img * 256 + oc] = r;
    }
  }
  __syncthreads();

  // ---- e[img,c] = dot(feat, tw[c,:]) + tb[c]  (support images only) ----
  if (img < 100) {
    int c = t & 255, dq = t >> 8;
    float acc = 0.f;
#pragma unroll 4
    for (int ii = 0; ii < 64; ii++) {
      int d = dq * 64 + ii;
      acc = fmaf(sft[d], twt[d * 256 + c], acc);
    }
    if (dq) RED[(dq - 1) * 256 + c] = acc;
    __syncthreads();
    if (dq == 0)
      e_buf[img * 256 + c] = acc + RED[c] + RED[256 + c] + RED[512 + c] + tb[c];
  }
}

// ---- Kernel 3: 3-iter routing, 10 blocks ----
__global__ void k_routing(const float* __restrict__ e, float* __restrict__ proto) {
  int n = blockIdx.x;
  __shared__ float sb[10], sdc[10], red[4], red2[40], sfc[1];
  int t = threadIdx.x;
  int lane = t & 63, wid = t >> 6;
  float ek[10];
#pragma unroll
  for (int k = 0; k < 10; k++) ek[k] = e[n * 2560 + k * 256 + t];
  if (t < 10) sb[t] = 0.f;
  __syncthreads();
  float cd = 0.f;
  for (int iter = 0; iter < 3; iter++) {
    if (t == 0) {
      float mx = sb[0];
      for (int k = 1; k < 10; k++) mx = fmaxf(mx, sb[k]);
      float sum = 0.f;
      for (int k = 0; k < 10; k++) { float ex = expf(sb[k] - mx); sdc[k] = ex; sum += ex; }
      float inv = 1.f / sum;
      for (int k = 0; k < 10; k++) sdc[k] *= inv;
    }
    __syncthreads();
    cd = 0.f;
#pragma unroll
    for (int k = 0; k < 10; k++) cd = fmaf(sdc[k], ek[k], cd);
    float ss = cd * cd;
#pragma unroll
    for (int off = 32; off > 0; off >>= 1) ss += __shfl_down(ss, off, 64);
    if (lane == 0) red[wid] = ss;
    __syncthreads();
    if (t == 0) {
      float tot = red[0] + red[1] + red[2] + red[3];
      sfc[0] = sqrtf(tot) / (tot + 1.f);
    }
    __syncthreads();
    cd *= sfc[0];
    float pr[10];
#pragma unroll
    for (int k = 0; k < 10; k++) pr[k] = cd * ek[k];
#pragma unroll
    for (int off = 32; off > 0; off >>= 1)
#pragma unroll
      for (int k = 0; k < 10; k++) pr[k] += __shfl_down(pr[k], off, 64);
    if (lane == 0)
#pragma unroll
      for (int k = 0; k < 10; k++) red2[k * 4 + wid] = pr[k];
    __syncthreads();
    if (t < 10) sb[t] += red2[t * 4] + red2[t * 4 + 1] + red2[t * 4 + 2] + red2[t * 4 + 3];
    __syncthreads();
  }
  proto[n * 256 + t] = cd;
}

// ---- Kernel 4: t1[n,h,e] += proto-chunk . bil_w. 800 blocks ----
__global__ void k_t1(const float* __restrict__ proto, const float* __restrict__ bw,
                     float* __restrict__ t1) {
  int b = blockIdx.x;
  int h = b >> 3, c0 = (b & 7) * 32;
  int e = threadIdx.x;
  __shared__ float sp[320];
  for (int i = e; i < 320; i += 256) {
    int n = i >> 5, cl = i & 31;
    sp[i] = proto[n * 256 + c0 + cl];
  }
  __syncthreads();
  float acc[10];
#pragma unroll
  for (int n = 0; n < 10; n++) acc[n] = 0.f;
  const float* wp = bw + ((size_t)h * 256 + c0) * 256 + e;
#pragma unroll 4
  for (int cl = 0; cl < 32; cl++) {
    float wv = wp[(size_t)cl * 256];
#pragma unroll
    for (int n = 0; n < 10; n++) acc[n] = fmaf(sp[n * 32 + cl], wv, acc[n]);
  }
#pragma unroll
  for (int n = 0; n < 10; n++)
    atomicAdd(&t1[((size_t)n * 100 + h) * 256 + e], acc[n]);
}

// ---- Kernel 5: score + log_softmax. 150 blocks (one per q) ----
__global__ void k_score(const float* __restrict__ t1, const float* __restrict__ qf,
                        const float* __restrict__ sw, const float* __restrict__ sbp,
                        float* __restrict__ out) {
  int q = blockIdx.x;
  int t = threadIdx.x, lane = t & 63, wid = t >> 6;
  __shared__ float sred[40];
  float4 qv = *(const float4*)(qf + q * 256 + lane * 4);
  float accn[10];
#pragma unroll
  for (int n = 0; n < 10; n++) accn[n] = 0.f;
  for (int h = wid * 25; h < wid * 25 + 25; h++) {
    float swh = sw[h];
#pragma unroll
    for (int n = 0; n < 10; n++) {
      float4 tv = *(const float4*)(t1 + ((size_t)n * 100 + h) * 256 + lane * 4);
      float pr = tv.x * qv.x + tv.y * qv.y + tv.z * qv.z + tv.w * qv.w;
#pragma unroll
      for (int off = 32; off > 0; off >>= 1) pr += __shfl_down(pr, off, 64);
      if (lane == 0) accn[n] = fmaf(fmaxf(pr, 0.f), swh, accn[n]);
    }
  }
  if (lane == 0)
#pragma unroll
    for (int n = 0; n < 10; n++) sred[wid * 10 + n] = accn[n];
  __syncthreads();
  if (t == 0) {
    float s[10];
    float mx = -1e30f;
    for (int n = 0; n < 10; n++) {
      s[n] = sred[n] + sred[10 + n] + sred[20 + n] + sred[30 + n] + sbp[0];
      mx = fmaxf(mx, s[n]);
    }
    float sum = 0.f;
    for (int n = 0; n < 10; n++) sum += expf(s[n] - mx);
    float lse = mx + logf(sum);
    for (int n = 0; n < 10; n++) out[q * 10 + n] = s[n] - lse;
  }
}

extern "C" void kernel_launch(void* const* d_in, const int* in_sizes, int n_in,
                              void* d_out, int out_size, void* d_ws, size_t ws_size,
                              hipStream_t stream) {
  const float* support = (const float*)d_in[0];
  const float* query   = (const float*)d_in[1];
  const float* conv_w[5]; const float* bn_g[5]; const float* bn_b[5];
  for (int i = 0; i < 5; i++) {
    conv_w[i] = (const float*)d_in[2 + 3 * i];
    bn_g[i]   = (const float*)d_in[3 + 3 * i];
    bn_b[i]   = (const float*)d_in[4 + 3 * i];
  }
  const float* trans_w = (const float*)d_in[17];
  const float* trans_b = (const float*)d_in[18];
  const float* bil_w   = (const float*)d_in[19];
  const float* score_w = (const float*)d_in[20];
  const float* score_b = (const float*)d_in[21];
  float* out = (float*)d_out;
  float* ws = (float*)d_ws;

  float* feats = ws + OFF_FEATS;
  float* e_buf = ws + OFF_E;
  float* proto = ws + OFF_PROTO;
  float* t1    = ws + OFF_T1;

  k_block0<<<1000, 256, 0, stream>>>(support, query, conv_w[0], bn_g[0], bn_b[0],
                                     conv_w[1], conv_w[2], conv_w[3], conv_w[4],
                                     trans_w, ws);
  k_mid<<<250, 1024, 0, stream>>>(bn_g[1], bn_b[1], bn_g[2], bn_b[2],
                                  bn_g[3], bn_b[3], bn_g[4], bn_b[4],
                                  trans_b, ws, feats, e_buf);
  k_routing<<<10, 256, 0, stream>>>(e_buf, proto);
  k_t1<<<800, 256, 0, stream>>>(proto, bil_w, t1);
  k_score<<<150, 256, 0, stream>>>(t1, feats + 100 * 256, score_w, score_b, out);
}